// Round 3
// baseline (140.234 us; speedup 1.0000x reference)
//
#include <hip/hip_runtime.h>

constexpr int BSZ = 512;
constexpr int DIM = 128;
constexpr int NREG = 6;                 // 6*64 = 384 register-cached negative slots
#define MARGIN_F 0.2f
#define EPS_F 1e-6f

struct Accum { double num; unsigned long long den; unsigned int done; unsigned int pad; };

__global__ void triplet_init(Accum* __restrict__ g) {
  g->num = 0.0; g->den = 0ull; g->done = 0u; g->pad = 0u;
}

// One block (512 threads = 8 waves) per anchor i.
// Phase 1: thread t computes D[i,t]; ballot-compacts into apos (+margin) / bneg.
// Phase 2: each lane register-caches 6 negatives; waves stride over positives
//          read as uniform-address float4 broadcasts from LDS.
// Finish:  global atomic accumulate; last block writes out = num/den.
__global__ __launch_bounds__(512, 4) void triplet_main(
    const float* __restrict__ feat, const int* __restrict__ mask,
    Accum* __restrict__ g, float* __restrict__ out, int nblocks) {
  const int i = blockIdx.x;
  const int tid = threadIdx.x;
  const int wave = tid >> 6;
  const int lane = tid & 63;

  __shared__ float fis[DIM];        // anchor row + EPS folded in
  __shared__ float apos[BSZ];       // compacted positives (+margin), pad -1e30
  __shared__ float bneg[BSZ];       // compacted negatives, padded to 384 w/ +1e30
  __shared__ int wtot[8][2];
  __shared__ float wred[8];

  if (tid < DIM / 4) {
    float4 v = ((const float4*)(feat + (size_t)i * DIM))[tid];
    fis[tid * 4 + 0] = v.x + EPS_F; fis[tid * 4 + 1] = v.y + EPS_F;
    fis[tid * 4 + 2] = v.z + EPS_F; fis[tid * 4 + 3] = v.w + EPS_F;
  }
  __syncthreads();

  // ---- Phase 1: distance for column t = tid, then ballot compaction ----
  const float4* fk = (const float4*)(feat + (size_t)tid * DIM);
  float s = 0.f;
#pragma unroll
  for (int d = 0; d < DIM / 4; ++d) {
    float4 v = fk[d];
    float x0 = fis[4 * d + 0] - v.x;
    float x1 = fis[4 * d + 1] - v.y;
    float x2 = fis[4 * d + 2] - v.z;
    float x3 = fis[4 * d + 3] - v.w;
    s = fmaf(x0, x0, s); s = fmaf(x1, x1, s);
    s = fmaf(x2, x2, s); s = fmaf(x3, x3, s);
  }
  const float dist = sqrtf(s);
  const int m = mask[(size_t)i * BSZ + tid];
  const bool is_pos = (m != 0);
  const bool is_neg = (m == 0) && (tid != i);

  const unsigned long long bp = __ballot(is_pos);
  const unsigned long long bn = __ballot(is_neg);
  const unsigned long long ltm = (1ull << lane) - 1ull;
  const int p_before = __popcll(bp & ltm);
  const int n_before = __popcll(bn & ltm);
  if (lane == 0) { wtot[wave][0] = __popcll(bp); wtot[wave][1] = __popcll(bn); }
  __syncthreads();

  int pbase = 0, nbase = 0, nP = 0, nN = 0;
#pragma unroll
  for (int w = 0; w < 8; ++w) {
    const int tp = wtot[w][0], tn = wtot[w][1];
    if (w < wave) { pbase += tp; nbase += tn; }
    nP += tp; nN += tn;
  }
  if (is_pos)      apos[pbase + p_before] = dist + MARGIN_F;
  else if (is_neg) bneg[nbase + n_before] = dist;

  const int nPpad = (nP + 31) & ~31;                 // mult of 32 -> nPpad/4 mult of 8
  { const int j = nP + tid; if (j < nPpad) apos[j] = -1e30f; }   // relu -> 0
  { const int k = nN + tid; if (k < NREG * 64) bneg[k] = 1e30f; } // relu -> 0
  __syncthreads();

  // ---- Phase 2: register-cached negatives, broadcast positives ----
  float bnr[NREG];
#pragma unroll
  for (int r = 0; r < NREG; ++r) bnr[r] = bneg[lane + 64 * r];

  float acc[NREG];
#pragma unroll
  for (int r = 0; r < NREG; ++r) acc[r] = 0.f;

  const float4* apos4 = (const float4*)apos;
  const int nj4 = nPpad >> 2;
  for (int j4 = wave; j4 < nj4; j4 += 8) {
    const float4 a = apos4[j4];                      // uniform addr: LDS broadcast
#pragma unroll
    for (int r = 0; r < NREG; ++r) {
      acc[r] += fmaxf(a.x - bnr[r], 0.f);
      acc[r] += fmaxf(a.y - bnr[r], 0.f);
      acc[r] += fmaxf(a.z - bnr[r], 0.f);
      acc[r] += fmaxf(a.w - bnr[r], 0.f);
    }
  }
  float lsum = 0.f;
#pragma unroll
  for (int r = 0; r < NREG; ++r) lsum += acc[r];

  if (nN > NREG * 64) {                              // rare statistical tail
    for (int j = wave; j < nP; j += 8) {
      const float aj = apos[j];
      for (int k = NREG * 64 + lane; k < nN; k += 64)
        lsum += fmaxf(aj - bneg[k], 0.f);
    }
  }

  // ---- Block reduction + device accumulate ----
  for (int off = 32; off > 0; off >>= 1) lsum += __shfl_down(lsum, off, 64);
  if (lane == 0) wred[wave] = lsum;
  __syncthreads();
  if (tid == 0) {
    float bsum = 0.f;
#pragma unroll
    for (int w = 0; w < 8; ++w) bsum += wred[w];
    atomicAdd(&g->num, (double)bsum);
    atomicAdd(&g->den, (unsigned long long)((long long)nP * (long long)nN));
    __threadfence();
    const unsigned int old = atomicAdd(&g->done, 1u);
    if (old == (unsigned int)(nblocks - 1)) {
      __threadfence();
      const double num = atomicAdd(&g->num, 0.0);            // device-scope read
      const unsigned long long den = atomicAdd(&g->den, 0ull);
      out[0] = (den > 0) ? (float)(num / (double)den) : 0.0f;
    }
  }
}

extern "C" void kernel_launch(void* const* d_in, const int* in_sizes, int n_in,
                              void* d_out, int out_size, void* d_ws, size_t ws_size,
                              hipStream_t stream) {
  const float* feat = (const float*)d_in[0];
  const int* mask = (const int*)d_in[1];
  float* out = (float*)d_out;
  Accum* g = (Accum*)d_ws;

  triplet_init<<<1, 1, 0, stream>>>(g);
  triplet_main<<<BSZ, 512, 0, stream>>>(feat, mask, g, out, BSZ);
}